// Round 12
// baseline (241.473 us; speedup 1.0000x reference)
//
#include <hip/hip_runtime.h>
#include <math.h>

#define NPG 256
#define EPG 4096
#define NG  512
#define FIN 128
#define HD  64
#define TOUT 18
#define KTOP 16
#define STA 68                    // h row stride; own-row b128s cover banks uniformly
#define SRCL_CAP (EPG + 3*NPG)
#define E_TOT (NG*EPG)

__device__ __forceinline__ float dot4(float4 a, float4 b) {
    return a.x*b.x + a.y*b.y + a.z*b.z + a.w*b.w;
}

__global__ __launch_bounds__(512)
__attribute__((amdgpu_waves_per_eu(4, 4)))   // exactly 4 waves/EU -> VGPR cap 128
void dgcnn_fused(
    const float* __restrict__ x,
    const int*   __restrict__ ei,
    const float* __restrict__ w0, const float* __restrict__ b0,
    const float* __restrict__ w1, const float* __restrict__ b1,
    const float* __restrict__ w2, const float* __restrict__ b2,
    const float* __restrict__ w3, const float* __restrict__ b3,
    const float* __restrict__ w4, const float* __restrict__ b4,
    const float* __restrict__ c1w, const float* __restrict__ c1b,
    const float* __restrict__ c2w, const float* __restrict__ c2b,
    const float* __restrict__ d1w, const float* __restrict__ d1b,
    const float* __restrict__ d2w, const float* __restrict__ d2b,
    float* __restrict__ out)
{
    __shared__ __align__(16) float s_h[NPG*STA];   // h_lin / h / proj+head (aliased)
    __shared__ unsigned char s_srcl[SRCL_CAP] __attribute__((aligned(4)));
    __shared__ int   s_off[NPG+1];
    __shared__ int   s_cnt[NPG];
    __shared__ float s_invdeg[NPG];
    __shared__ float s_lin5[NPG];
    __shared__ float s_h5[NPG];
    __shared__ int   s_sel[KTOP];
    int*   s_cur   = (int*)s_h;            // phase-0 alias
    int*   s_outd  = ((int*)s_h) + NPG;    // phase-0 alias
    float* s_proj  = s_h;                  // final alias: [256][20] proj rows
    float* s_headf = s_h + 8192;           // head scratch

    const int g    = blockIdx.x;
    const int t    = threadIdx.x;
    const int lane = t & 63;
    const int wid  = t >> 6;                        // 0..7
    const int nb   = t & 127;
    const int n0   = nb;                            // owned node A
    const int n1   = nb + 128;                      // owned node B
    const int cb   = __builtin_amdgcn_readfirstlane((t >> 7) * 16);  // 16 mm channels
    const int po   = __builtin_amdgcn_readfirstlane((t >> 7) * 4);   // 4 proj channels
    const int js   = lane >> 4;
    const int q4   = (lane & 15) << 2;
    const int gbase = g * NPG;
    const int* __restrict__ srcg = ei + (size_t)g * EPG;
    const int* __restrict__ dstg = ei + (size_t)E_TOT + (size_t)g * EPG;

    // ---------------- phase 0: degrees + 4-padded CSR (by dst) ----------------
    if (t < NPG) { s_cnt[t] = 0; s_outd[t] = 0; }
    __syncthreads();
    for (int e = t; e < EPG; e += 512) {
        int s = srcg[e] - gbase, d = dstg[e] - gbase;
        atomicAdd(&s_outd[s], 1);
        atomicAdd(&s_cnt[d], 1);
    }
    __syncthreads();
    if (t < NPG) s_invdeg[t] = __fdividef(1.0f, (float)(s_outd[t] + 1));
    if (wid == 0) {
        int p4 = lane * 4;
        int c0_ = s_cnt[p4], c1_ = s_cnt[p4+1], c2_ = s_cnt[p4+2], c3_ = s_cnt[p4+3];
        int q0 = (c0_+3)&~3, q1 = (c1_+3)&~3, q2 = (c2_+3)&~3, q3 = (c3_+3)&~3;
        int tot = q0+q1+q2+q3;
        int run = tot;
        #pragma unroll
        for (int o = 1; o < 64; o <<= 1) {
            int v = __shfl_up(run, o);
            if (lane >= o) run += v;
        }
        int base = run - tot;
        s_off[p4]   = base;
        s_off[p4+1] = base + q0;
        s_off[p4+2] = base + q0 + q1;
        s_off[p4+3] = base + q0 + q1 + q2;
        if (lane == 63) s_off[NPG] = run;
    }
    __syncthreads();
    if (t < NPG) s_cur[t] = s_off[t];
    __syncthreads();
    for (int e = t; e < EPG; e += 512) {
        int s = srcg[e] - gbase, d = dstg[e] - gbase;
        int pos = atomicAdd(&s_cur[d], 1);
        s_srcl[pos] = (unsigned char)s;
    }
    __syncthreads();
    if (t < NPG) {                                   // pad to x4 with sentinel src=t
        int pe = s_off[t+1];
        for (int p = s_cur[t]; p < pe; p++) s_srcl[p] = (unsigned char)t;
    }
    __syncthreads();                                 // CSR done; s_h aliases dead

    float projacc[2][4];
    #pragma unroll
    for (int i = 0; i < 2; i++)
        #pragma unroll
        for (int p = 0; p < 4; p++) projacc[i][p] = 0.f;

    // agg (in place): h[d] = tanh(invdeg*(sum_src hl[src] + hl[d])); results in regs
    auto aggregate = [&]() {
        float4 res[8];
        #pragma unroll
        for (int r = 0; r < 8; r++) {
            int d = (wid + 8*r)*4 + js;
            int off = s_off[d], pe = s_off[d+1];
            int npad = (pe - off) - s_cnt[d];
            float4 a = *(const float4*)&s_h[d*STA + q4];
            float cf = (float)(1 - npad);
            a.x *= cf; a.y *= cf; a.z *= cf; a.w *= cf;
            for (int e = off; e < pe; e += 4) {
                unsigned sq = *(const unsigned*)&s_srcl[e];
                #pragma unroll
                for (int m = 0; m < 4; m++) {
                    int src = (sq >> (8*m)) & 255;
                    float4 hv = *(const float4*)&s_h[src*STA + q4];
                    a.x += hv.x; a.y += hv.y; a.z += hv.z; a.w += hv.w;
                }
            }
            float id = s_invdeg[d];
            res[r].x = tanhf(a.x * id); res[r].y = tanhf(a.y * id);
            res[r].z = tanhf(a.z * id); res[r].w = tanhf(a.w * id);
        }
        __syncthreads();                             // all reads of h_lin complete
        #pragma unroll
        for (int r = 0; r < 8; r++) {
            int d = (wid + 8*r)*4 + js;
            *(float4*)&s_h[d*STA + q4] = res[r];
        }
        __syncthreads();
    };

    // hidden matmul (64->64) + folded conv1-proj; 2 nodes x 16 ch per thread.
    // Rows: 2 own-row b128/kq (scalar float4s, no kq-indexed reg array).
    // Weights: wave-uniform s_load (K$-hot), reused across both nodes.
    auto mmHidden = [&](const float* __restrict__ w, const float* __restrict__ b,
                        const float* __restrict__ c1s) {
        float acc0[16], acc1[16];
        #pragma unroll
        for (int j = 0; j < 16; j++) { float bv = b[cb + j]; acc0[j] = bv; acc1[j] = bv; }
        #pragma unroll 2
        for (int kq = 0; kq < 16; kq++) {
            float4 r0 = *(const float4*)&s_h[n0*STA + kq*4];
            float4 r1 = *(const float4*)&s_h[n1*STA + kq*4];
            #pragma unroll
            for (int j = 0; j < 16; j++) {
                float4 wq = *(const float4*)(w + (cb+j)*HD + kq*4);
                acc0[j] += dot4(r0, wq);
                acc1[j] += dot4(r1, wq);
            }
            #pragma unroll
            for (int p = 0; p < 4; p++) {
                const float* cr = c1s + (po+p)*257 + kq*4;
                projacc[0][p] += r0.x*cr[0] + r0.y*cr[1] + r0.z*cr[2] + r0.w*cr[3];
                projacc[1][p] += r1.x*cr[0] + r1.y*cr[1] + r1.z*cr[2] + r1.w*cr[3];
            }
        }
        __syncthreads();                             // all row reads complete
        #pragma unroll
        for (int j4 = 0; j4 < 4; j4++) {
            float4 v0 = {acc0[4*j4], acc0[4*j4+1], acc0[4*j4+2], acc0[4*j4+3]};
            float4 v1 = {acc1[4*j4], acc1[4*j4+1], acc1[4*j4+2], acc1[4*j4+3]};
            *(float4*)&s_h[n0*STA + cb + 4*j4] = v0;
            *(float4*)&s_h[n1*STA + cb + 4*j4] = v1;
        }
        __syncthreads();
    };

    // ---------------- layer 0 (F=128; x rows read directly from global) -------
    {
        float acc0[16], acc1[16];
        #pragma unroll
        for (int j = 0; j < 16; j++) { float bv = b0[cb + j]; acc0[j] = bv; acc1[j] = bv; }
        const float* xr0 = x + (size_t)(gbase + n0) * FIN;
        const float* xr1 = x + (size_t)(gbase + n1) * FIN;
        #pragma unroll 2
        for (int kq = 0; kq < 32; kq++) {
            float4 r0 = *(const float4*)&xr0[kq*4];
            float4 r1 = *(const float4*)&xr1[kq*4];
            #pragma unroll
            for (int j = 0; j < 16; j++) {
                float4 wq = *(const float4*)(w0 + (cb+j)*FIN + kq*4);
                acc0[j] += dot4(r0, wq);
                acc1[j] += dot4(r1, wq);
            }
        }
        #pragma unroll
        for (int j4 = 0; j4 < 4; j4++) {
            float4 v0 = {acc0[4*j4], acc0[4*j4+1], acc0[4*j4+2], acc0[4*j4+3]};
            float4 v1 = {acc1[4*j4], acc1[4*j4+1], acc1[4*j4+2], acc1[4*j4+3]};
            *(float4*)&s_h[n0*STA + cb + 4*j4] = v0;
            *(float4*)&s_h[n1*STA + cb + 4*j4] = v1;
        }
        __syncthreads();
    }
    aggregate();                                     // -> h0

    mmHidden(w1, b1, c1w);                           // h0 -> hl1, proj slice 0
    aggregate();                                     // -> h1
    mmHidden(w2, b2, c1w + 64);                      // h1 -> hl2, proj slice 64
    aggregate();                                     // -> h2
    mmHidden(w3, b3, c1w + 128);                     // h2 -> hl3, proj slice 128
    aggregate();                                     // -> h3

    // ---------------- layer 4 (64->1) + proj slice 192 -----------------------
    {
        float l50 = 0.f, l51 = 0.f;
        #pragma unroll 2
        for (int kq = 0; kq < 16; kq++) {
            float4 r0 = *(const float4*)&s_h[n0*STA + kq*4];
            float4 r1 = *(const float4*)&s_h[n1*STA + kq*4];
            #pragma unroll
            for (int p = 0; p < 4; p++) {
                const float* cr = c1w + (po+p)*257 + 192 + kq*4;
                projacc[0][p] += r0.x*cr[0] + r0.y*cr[1] + r0.z*cr[2] + r0.w*cr[3];
                projacc[1][p] += r1.x*cr[0] + r1.y*cr[1] + r1.z*cr[2] + r1.w*cr[3];
            }
            if (cb == 0) {
                float4 w4q = *(const float4*)&w4[kq*4];
                l50 += dot4(r0, w4q);
                l51 += dot4(r1, w4q);
            }
        }
        if (cb == 0) {
            float b4v = b4[0];
            s_lin5[n0] = l50 + b4v;
            s_lin5[n1] = l51 + b4v;
        }
        __syncthreads();                             // h3 reads done; lin5 ready
        if (t < NPG) {
            int d = t;
            int off = s_off[d], pe = s_off[d+1];
            int npad = (pe - off) - s_cnt[d];
            float a = (float)(1 - npad) * s_lin5[d];
            for (int e = off; e < pe; e += 4) {
                unsigned sq = *(const unsigned*)&s_srcl[e];
                a += s_lin5[sq & 255] + s_lin5[(sq>>8)&255]
                   + s_lin5[(sq>>16)&255] + s_lin5[(sq>>24)&255];
            }
            s_h5[d] = tanhf(a * s_invdeg[d]);
        }
        __syncthreads();
        {   // finalize proj with h5 term; store proj rows (s_h alias safe now)
            float h50 = s_h5[n0], h51 = s_h5[n1];
            #pragma unroll
            for (int p = 0; p < 4; p++) {
                float cw = c1w[(po+p)*257 + 256];
                s_proj[n0*20 + po + p] = projacc[0][p] + h50*cw;
                s_proj[n1*20 + po + p] = projacc[1][p] + h51*cw;
            }
        }
        if (wid == 0) {                              // top-16: desc value, asc index ties
            float v[4]; int idx[4];
            int p4 = lane * 4;
            #pragma unroll
            for (int j = 0; j < 4; j++) { idx[j] = p4 + j; v[j] = s_h5[p4 + j]; }
            for (int r = 0; r < KTOP; r++) {
                float bv = v[0]; int bi = idx[0];
                #pragma unroll
                for (int j = 1; j < 4; j++)
                    if (v[j] > bv || (v[j] == bv && idx[j] < bi)) { bv = v[j]; bi = idx[j]; }
                #pragma unroll
                for (int o = 32; o > 0; o >>= 1) {
                    float ov = __shfl_xor(bv, o);
                    int   oi = __shfl_xor(bi, o);
                    if (ov > bv || (ov == bv && oi < bi)) { bv = ov; bi = oi; }
                }
                if ((bi >> 2) == lane) v[bi & 3] = -1e30f;
                if (lane == 0) s_sel[r] = bi;
            }
        }
    }
    __syncthreads();

    // ---------------- head ----------------
    float* s_c1   = s_headf;        // [16 o][16 slot]
    float* s_p1   = s_headf + 256;  // [16 o][8]
    float* s_flat = s_headf + 384;  // 128
    float* s_last = s_headf + 512;  // 32
    float* s_outv = s_headf + 544;  // 18

    if (t < 256) {
        int sl = t >> 4, o = t & 15;
        float vv = s_proj[s_sel[sl]*20 + o] + c1b[o];
        s_c1[o*16 + sl] = fmaxf(vv, 0.f);
    }
    __syncthreads();
    if (t < 128) {
        int o = t >> 3, j = t & 7;
        s_p1[o*8 + j] = fmaxf(s_c1[o*16 + 2*j], s_c1[o*16 + 2*j + 1]);
    }
    __syncthreads();
    if (t < 128) {
        int oc = t >> 2, tt = t & 3;
        float a = c2b[oc];
        #pragma unroll
        for (int ic = 0; ic < 16; ic++)
            #pragma unroll
            for (int kk = 0; kk < 5; kk++)
                a += s_p1[ic*8 + tt + kk] * c2w[(oc*16 + ic)*5 + kk];
        s_flat[oc*4 + tt] = fmaxf(a, 0.f);
    }
    __syncthreads();
    if (t < 32) {
        float a = d1b[t];
        #pragma unroll
        for (int i = 0; i < 128; i++) a += s_flat[i] * d1w[t*128 + i];
        a = fmaxf(a, 0.f);
        s_last[t] = a;
        out[2*NG*TOUT + g*32 + t] = a;               // output 2: last
    }
    __syncthreads();
    if (t < TOUT) {
        float a = d2b[t];
        #pragma unroll
        for (int j = 0; j < 32; j++) a += s_last[j] * d2w[t*32 + j];
        s_outv[t] = a;
        out[NG*TOUT + g*TOUT + t] = a;               // output 1: logits
    }
    __syncthreads();
    if (t < TOUT) {
        float m = s_outv[0];
        for (int i = 1; i < TOUT; i++) m = fmaxf(m, s_outv[i]);
        float sum = 0.f;
        for (int i = 0; i < TOUT; i++) sum += expf(s_outv[i] - m);
        out[g*TOUT + t] = s_outv[t] - m - logf(sum); // output 0: log_softmax
    }
}

extern "C" void kernel_launch(void* const* d_in, const int* in_sizes, int n_in,
                              void* d_out, int out_size, void* d_ws, size_t ws_size,
                              hipStream_t stream) {
    (void)in_sizes; (void)n_in; (void)out_size; (void)d_ws; (void)ws_size;
    const float* x   = (const float*)d_in[0];
    const int*   ei  = (const int*)  d_in[1];
    const float* w0  = (const float*)d_in[4];  const float* b0 = (const float*)d_in[5];
    const float* w1  = (const float*)d_in[6];  const float* b1 = (const float*)d_in[7];
    const float* w2  = (const float*)d_in[8];  const float* b2 = (const float*)d_in[9];
    const float* w3  = (const float*)d_in[10]; const float* b3 = (const float*)d_in[11];
    const float* w4  = (const float*)d_in[12]; const float* b4 = (const float*)d_in[13];
    const float* c1w = (const float*)d_in[14]; const float* c1b = (const float*)d_in[15];
    const float* c2w = (const float*)d_in[16]; const float* c2b = (const float*)d_in[17];
    const float* d1w = (const float*)d_in[18]; const float* d1b = (const float*)d_in[19];
    const float* d2w = (const float*)d_in[20]; const float* d2b = (const float*)d_in[21];
    float* out = (float*)d_out;

    dgcnn_fused<<<NG, 512, 0, stream>>>(x, ei,
        w0, b0, w1, b1, w2, b2, w3, b3, w4, b4,
        c1w, c1b, c2w, c2b, d1w, d1b, d2w, d2b, out);
}